// Round 13
// baseline (321.370 us; speedup 1.0000x reference)
//
#include <hip/hip_runtime.h>

// Gaussian pyramid, 4 levels. Input (16,3,1024,1024) f32.
// Level0 copy fused into level-1 reduce. Level k+1 = replicate-pad-2 +
// separable 5x5, stride 2.
//
// R12 found WRITE_SIZE = 1.7x ideal: 16-B stores at 32-B lane stride don't
// merge into full lines. R13: per-lane ownership = 2 output px so EVERY
// instruction is dense (lane stride == access size):
//   loads: 4x dwordx4, 16-B lane stride (instructions overlap -> L1 hits)
//   out0 copy: 1x dwordx4 per row, 16-B lane stride (the lane's own B reg)
//   out1:      1x dwordx2, 8-B lane stride
// Keeps R11's champion structure: R=8 sliding window + explicit prefetch,
// branchless edge remap (now 3 special lanes/row: left, right-1, right-2).

struct Row4 { float4 A, B, C, D; };

template <int WIN>
__device__ __forceinline__ Row4 load4(const float* ip, int iy, int xb) {
    const float4* p = (const float4*)(ip + (size_t)iy * WIN + xb);
    Row4 r; r.A = p[0]; r.B = p[1]; r.C = p[2]; r.D = p[3];
    return r;
}

// Window of 7 input floats (x = 4g-2 .. 4g+4, replicate-clamped) + the lane's
// owned copy float4 (input x [4g, 4g+4)).
// Loads were taken from clamped base xb: interior xb=4g-4; L: xb=0;
// R1 (4g==WIN-8) and R2 (4g==WIN-4): xb=WIN-16.
__device__ __forceinline__ void extract(const Row4& r, bool L, bool R1, bool R2,
                                        float w[7], float4& cp) {
    w[0] = L ? r.A.x : R1 ? r.B.z : R2 ? r.C.z : r.A.z;
    w[1] = L ? r.A.x : R1 ? r.B.w : R2 ? r.C.w : r.A.w;
    w[2] = L ? r.A.x : R1 ? r.C.x : R2 ? r.D.x : r.B.x;
    w[3] = L ? r.A.y : R1 ? r.C.y : R2 ? r.D.y : r.B.y;
    w[4] = L ? r.A.z : R1 ? r.C.z : R2 ? r.D.z : r.B.z;
    w[5] = L ? r.A.w : R1 ? r.C.w : R2 ? r.D.w : r.B.w;
    w[6] = L ? r.B.x : R1 ? r.D.x : R2 ? r.D.w : r.C.x;
    cp.x = L ? r.A.x : R1 ? r.C.x : R2 ? r.D.x : r.B.x;
    cp.y = L ? r.A.y : R1 ? r.C.y : R2 ? r.D.y : r.B.y;
    cp.z = L ? r.A.z : R1 ? r.C.z : R2 ? r.D.z : r.B.z;
    cp.w = L ? r.A.w : R1 ? r.C.w : R2 ? r.D.w : r.B.w;
}

__device__ __forceinline__ float2 hconv2(const float w[7]) {
    const float k0 = 0.0625f, k1 = 0.25f, k2 = 0.375f;
    float2 h;
    h.x = k0 * (w[0] + w[4]) + k1 * (w[1] + w[3]) + k2 * w[2];
    h.y = k0 * (w[2] + w[6]) + k1 * (w[3] + w[5]) + k2 * w[4];
    return h;
}

template <int R, int HIN, int WIN, bool FUSE>
__global__ __launch_bounds__(256) void gpyr_slide(
        const float* __restrict__ in,
        float* __restrict__ out0,
        float* __restrict__ out1) {
    constexpr int HOUT = HIN / 2, WOUT = WIN / 2;
    const int tx = threadIdx.x, ty = threadIdx.y;
    const int g   = blockIdx.x * 64 + tx;       // lane's x-group: 4 input floats
    const int Y0  = (blockIdx.y * blockDim.y + ty) * R;
    const int img = blockIdx.z;

    const int x4 = 4 * g;                       // owned input x base
    const bool L  = (g == 0);
    const bool R1 = (x4 == WIN - 8);
    const bool R2 = (x4 == WIN - 4);
    int xb = x4 - 4;
    if (L) xb = 0;
    if (R1 || R2) xb = WIN - 16;

    const float* ip = in + (size_t)img * HIN * WIN;
    float* o1 = out1 + (size_t)img * HOUT * WOUT;
    float* o0 = out0 + (size_t)img * HIN * WIN;

    // Prologue: rows 2Y0-2, 2Y0-1, 2Y0.
    float2 hs0, hs1, hs2;
    float4 cpE;                                  // copy data for even row 2*oy
    {
        Row4 t0 = load4<WIN>(ip, max(2 * Y0 - 2, 0), xb);
        Row4 t1 = load4<WIN>(ip, max(2 * Y0 - 1, 0), xb);
        Row4 t2 = load4<WIN>(ip, 2 * Y0, xb);
        float w[7]; float4 cp;
        extract(t0, L, R1, R2, w, cp); hs0 = hconv2(w);
        extract(t1, L, R1, R2, w, cp); hs1 = hconv2(w);
        extract(t2, L, R1, R2, w, cpE); hs2 = hconv2(w);
    }

    // Iteration-0 rows.
    Row4 ra = load4<WIN>(ip, 2 * Y0 + 1, xb);
    Row4 rb = load4<WIN>(ip, min(2 * Y0 + 2, HIN - 1), xb);

    const float k0 = 0.0625f, k1 = 0.25f, k2 = 0.375f;

#pragma unroll
    for (int i = 0; i < R; ++i) {
        const int oy = Y0 + i;

        // Prefetch next iteration's rows before consuming current ones.
        Row4 ran, rbn;
        if (i + 1 < R) {
            ran = load4<WIN>(ip, 2 * oy + 3, xb);
            rbn = load4<WIN>(ip, min(2 * oy + 4, HIN - 1), xb);
        }

        // Even-row copy (data saved last iteration; independent of new loads).
        if (FUSE) {
            *(float4*)(o0 + (size_t)(2 * oy) * WIN + x4) = cpE;
        }

        float wa[7]; float4 cpA;
        extract(ra, L, R1, R2, wa, cpA);
        if (FUSE) {
            *(float4*)(o0 + (size_t)(2 * oy + 1) * WIN + x4) = cpA;
        }
        float2 ha = hconv2(wa);

        float wb[7]; float4 cpB;
        extract(rb, L, R1, R2, wb, cpB);
        float2 hb = hconv2(wb);
        cpE = cpB;                               // row 2*oy+2 = next even row

        float2 o;
        o.x = k0 * (hs0.x + hb.x) + k1 * (hs1.x + ha.x) + k2 * hs2.x;
        o.y = k0 * (hs0.y + hb.y) + k1 * (hs1.y + ha.y) + k2 * hs2.y;
        *(float2*)(o1 + (size_t)oy * WOUT + 2 * g) = o;

        hs0 = hs2; hs1 = ha; hs2 = hb;
        ra = ran; rb = rbn;
    }
}

extern "C" void kernel_launch(void* const* d_in, const int* in_sizes, int n_in,
                              void* d_out, int out_size, void* d_ws, size_t ws_size,
                              hipStream_t stream) {
    const float* im = (const float*)d_in[0];
    float* out = (float*)d_out;

    const int NC = 16 * 3;
    const size_t L0 = (size_t)NC * 1024 * 1024;
    const size_t L1 = (size_t)NC * 512 * 512;
    const size_t L2 = (size_t)NC * 256 * 256;

    float* out0 = out;
    float* out1 = out0 + L0;
    float* out2 = out1 + L1;
    float* out3 = out2 + L2;

    // Level 0+1 fused: 512x512 out. 256 lanes/row (2 px each), R=8.
    {
        dim3 block(64, 4, 1);
        dim3 grid(4, 512 / (4 * 8), NC);       // (4, 16, 48) = 3072
        gpyr_slide<8, 1024, 1024, true><<<grid, block, 0, stream>>>(im, out0, out1);
    }
    // Level 2: 256x256 out. 128 lanes/row, R=4.
    {
        dim3 block(64, 4, 1);
        dim3 grid(2, 256 / (4 * 4), NC);       // (2, 16, 48) = 1536
        gpyr_slide<4, 512, 512, false><<<grid, block, 0, stream>>>(out1, nullptr, out2);
    }
    // Level 3: 128x128 out. 64 lanes/row, R=2.
    {
        dim3 block(64, 4, 1);
        dim3 grid(1, 128 / (4 * 2), NC);       // (1, 16, 48) = 768
        gpyr_slide<2, 256, 256, false><<<grid, block, 0, stream>>>(out2, nullptr, out3);
    }
}

// Round 14
// 306.225 us; speedup vs baseline: 1.0495x; 1.0495x over previous
//
#include <hip/hip_runtime.h>

// Gaussian pyramid, 4 levels. Input (16,3,1024,1024) f32.
// Level0 copy fused into level-1 reduce. Level k+1 = replicate-pad-2 +
// separable 5x5, stride 2.
//
// R13 lesson (counters): float w[7] arrays passed by pointer -> compiler
// promoted allocas to LDS (16KB/block, 8.8e7 bank conflicts) + spill traffic.
// R14: same 2px/lane dense-instruction geometry, but SCALARS ONLY — no
// arrays, no pointer out-params. Every memory instruction is dense:
//   loads: 3x dwordx4/row, 16-B lane stride
//   out0:  1x dwordx4/row/lane (the lane's owned 4 floats)
//   out1:  1x dwordx2/lane
// Only 2 special lanes per row (g==0, g==last); handled by 2-deep selects.

struct R12f { float4 A, B, C; };            // 12 consecutive input floats
struct W7 { float w0, w1, w2, w3, w4, w5, w6; float4 cp; };

template <int WIN>
__device__ __forceinline__ R12f load3(const float* ip, int iy, int xb) {
    const float4* p = (const float4*)(ip + (size_t)iy * WIN + xb);
    R12f r; r.A = p[0]; r.B = p[1]; r.C = p[2];
    return r;
}

// Window w0..w6 = input x = 4g-2 .. 4g+4 (replicate-clamped), cp = owned
// floats [4g, 4g+4).  interior: xb=4g-4 -> w=[A.z,A.w,B.x,B.y,B.z,B.w,C.x], cp=B
// L  (g==0,  xb=0):      w=[A.x,A.x,A.x,A.y,A.z,A.w,B.x], cp=A
// Rr (g==last,xb=4g-8):  w=[B.z,B.w,C.x,C.y,C.z,C.w,C.w], cp=C
__device__ __forceinline__ W7 extract(const R12f& r, bool L, bool Rr) {
    W7 o;
    o.w0 = L ? r.A.x : (Rr ? r.B.z : r.A.z);
    o.w1 = L ? r.A.x : (Rr ? r.B.w : r.A.w);
    o.w2 = L ? r.A.x : (Rr ? r.C.x : r.B.x);
    o.w3 = L ? r.A.y : (Rr ? r.C.y : r.B.y);
    o.w4 = L ? r.A.z : (Rr ? r.C.z : r.B.z);
    o.w5 = L ? r.A.w : (Rr ? r.C.w : r.B.w);
    o.w6 = L ? r.B.x : (Rr ? r.C.w : r.C.x);
    o.cp.x = L ? r.A.x : (Rr ? r.C.x : r.B.x);
    o.cp.y = L ? r.A.y : (Rr ? r.C.y : r.B.y);
    o.cp.z = L ? r.A.z : (Rr ? r.C.z : r.B.z);
    o.cp.w = L ? r.A.w : (Rr ? r.C.w : r.B.w);
    return o;
}

__device__ __forceinline__ float2 hconv2(const W7& w) {
    const float k0 = 0.0625f, k1 = 0.25f, k2 = 0.375f;
    float2 h;
    h.x = k0 * (w.w0 + w.w4) + k1 * (w.w1 + w.w3) + k2 * w.w2;   // out x=2g
    h.y = k0 * (w.w2 + w.w6) + k1 * (w.w3 + w.w5) + k2 * w.w4;   // out x=2g+1
    return h;
}

template <int R, int HIN, int WIN, bool FUSE>
__global__ __launch_bounds__(256) void gpyr_slide(
        const float* __restrict__ in,
        float* __restrict__ out0,
        float* __restrict__ out1) {
    constexpr int HOUT = HIN / 2, WOUT = WIN / 2;
    constexpr int GMAX = WIN / 4 - 1;
    const int tx = threadIdx.x, ty = threadIdx.y;
    const int g   = blockIdx.x * 64 + tx;      // lane's x-group (4 input floats)
    const int Y0  = (blockIdx.y * blockDim.y + ty) * R;
    const int img = blockIdx.z;

    const bool L  = (g == 0);
    const bool Rr = (g == GMAX);
    int xb = 4 * g - 4;
    if (L)  xb = 0;
    if (Rr) xb = 4 * g - 8;

    const float* ip = in + (size_t)img * HIN * WIN;
    float* o1 = out1 + (size_t)img * HOUT * WOUT;
    float* o0 = out0 + (size_t)img * HIN * WIN;

    // Prologue: rows 2Y0-2, 2Y0-1, 2Y0.
    float2 hs0, hs1, hs2;
    float4 cpE;                                 // copy data for even row 2*oy
    {
        R12f t0 = load3<WIN>(ip, max(2 * Y0 - 2, 0), xb);
        R12f t1 = load3<WIN>(ip, max(2 * Y0 - 1, 0), xb);
        R12f t2 = load3<WIN>(ip, 2 * Y0, xb);
        W7 e0 = extract(t0, L, Rr); hs0 = hconv2(e0);
        W7 e1 = extract(t1, L, Rr); hs1 = hconv2(e1);
        W7 e2 = extract(t2, L, Rr); hs2 = hconv2(e2);
        cpE = e2.cp;
    }

    // Iteration-0 rows.
    R12f ra = load3<WIN>(ip, 2 * Y0 + 1, xb);
    R12f rb = load3<WIN>(ip, min(2 * Y0 + 2, HIN - 1), xb);

    const float k0 = 0.0625f, k1 = 0.25f, k2 = 0.375f;

#pragma unroll
    for (int i = 0; i < R; ++i) {
        const int oy = Y0 + i;

        // Prefetch next iteration's rows before consuming current ones.
        R12f ran, rbn;
        if (i + 1 < R) {
            ran = load3<WIN>(ip, 2 * oy + 3, xb);
            rbn = load3<WIN>(ip, min(2 * oy + 4, HIN - 1), xb);
        }

        // Even-row copy (saved last iteration; independent of new loads).
        if (FUSE) {
            *(float4*)(o0 + (size_t)(2 * oy) * WIN + 4 * g) = cpE;
        }

        W7 ea = extract(ra, L, Rr);
        if (FUSE) {
            *(float4*)(o0 + (size_t)(2 * oy + 1) * WIN + 4 * g) = ea.cp;
        }
        float2 ha = hconv2(ea);

        W7 eb = extract(rb, L, Rr);
        float2 hb = hconv2(eb);
        cpE = eb.cp;                            // row 2*oy+2 = next even row

        float2 o;
        o.x = k0 * (hs0.x + hb.x) + k1 * (hs1.x + ha.x) + k2 * hs2.x;
        o.y = k0 * (hs0.y + hb.y) + k1 * (hs1.y + ha.y) + k2 * hs2.y;
        *(float2*)(o1 + (size_t)oy * WOUT + 2 * g) = o;

        hs0 = hs2; hs1 = ha; hs2 = hb;          // slide down 2 input rows
        ra = ran; rb = rbn;
    }
}

extern "C" void kernel_launch(void* const* d_in, const int* in_sizes, int n_in,
                              void* d_out, int out_size, void* d_ws, size_t ws_size,
                              hipStream_t stream) {
    const float* im = (const float*)d_in[0];
    float* out = (float*)d_out;

    const int NC = 16 * 3;
    const size_t L0 = (size_t)NC * 1024 * 1024;
    const size_t L1 = (size_t)NC * 512 * 512;
    const size_t L2 = (size_t)NC * 256 * 256;

    float* out0 = out;
    float* out1 = out0 + L0;
    float* out2 = out1 + L1;
    float* out3 = out2 + L2;

    // Level 0+1 fused: 512x512 out, 256 lanes/row (2 px each), R=8.
    {
        dim3 block(64, 4, 1);
        dim3 grid(4, 512 / (4 * 8), NC);       // (4, 16, 48) = 3072
        gpyr_slide<8, 1024, 1024, true><<<grid, block, 0, stream>>>(im, out0, out1);
    }
    // Level 2: 256x256 out, 128 lanes/row, R=4.
    {
        dim3 block(64, 4, 1);
        dim3 grid(2, 256 / (4 * 4), NC);       // (2, 16, 48) = 1536
        gpyr_slide<4, 512, 512, false><<<grid, block, 0, stream>>>(out1, nullptr, out2);
    }
    // Level 3: 128x128 out, 64 lanes/row, R=2.
    {
        dim3 block(64, 4, 1);
        dim3 grid(1, 128 / (4 * 2), NC);       // (1, 16, 48) = 768
        gpyr_slide<2, 256, 256, false><<<grid, block, 0, stream>>>(out2, nullptr, out3);
    }
}